// Round 16
// baseline (369.559 us; speedup 1.0000x reference)
//
#include <hip/hip_runtime.h>

#define BB 2
#define SS 1024
#define DD 1024
#define HH 16
#define KVH 4
#define HDD 64
#define EE 16
#define II 1408
#define TT (BB*SS)
#define EPS_ 1e-6f

typedef unsigned short u16;
typedef __bf16 bf16x8 __attribute__((ext_vector_type(8)));
typedef _Float16 f16x8 __attribute__((ext_vector_type(8)));
typedef float f32x4 __attribute__((ext_vector_type(4)));

__device__ __forceinline__ float wred_sum(float v) {
#pragma unroll
  for (int o = 32; o > 0; o >>= 1) v += __shfl_xor(v, o);
  return v;
}

__device__ __forceinline__ u16 f2b(float f) {
  __bf16 h = (__bf16)f;
  return __builtin_bit_cast(u16, h);
}

__device__ __forceinline__ bf16x8 ld_frag(const u16* p) {
  return __builtin_bit_cast(bf16x8, *(const uint4*)p);
}
__device__ __forceinline__ f16x8 ldh(const u16* p) {
  return __builtin_bit_cast(f16x8, *(const uint4*)p);
}

// fp16 split-2 with scaled residual: v ~= h0 + h1 * 2^-11 (error ~2^-22)
__device__ __forceinline__ void split2h(float v, u16* o0, u16* o1) {
  _Float16 a = (_Float16)v;
  float fa = (float)a;
  _Float16 b = (_Float16)((v - fa) * 2048.0f);
  *o0 = __builtin_bit_cast(u16, a);
  *o1 = __builtin_bit_cast(u16, b);
}

#define CVAL(fm, nf, r) (accm[fm][nf][r] + accx[fm][nf][r] * 4.8828125e-4f)

// ---------------- rmsnorm with split-2 fp16 output ----------------
__global__ __launch_bounds__(256) void k_rmsnorm_split2(const float* __restrict__ x,
    const float* __restrict__ w, u16* __restrict__ o0, u16* __restrict__ o1) {
  int row = blockIdx.x, tid = threadIdx.x;
  float4 v = ((const float4*)(x + (size_t)row * DD))[tid];
  float ss = v.x*v.x + v.y*v.y + v.z*v.z + v.w*v.w;
  ss = wred_sum(ss);
  __shared__ float red[4];
  if ((tid & 63) == 0) red[tid >> 6] = ss;
  __syncthreads();
  float tot = red[0] + red[1] + red[2] + red[3];
  float sc = rsqrtf(tot * (1.0f / DD) + EPS_);
  float4 wv = ((const float4*)w)[tid];
  float vals[4] = {v.x*sc*wv.x, v.y*sc*wv.y, v.z*sc*wv.z, v.w*sc*wv.w};
  ushort4 s0, s1;
  split2h(vals[0], &s0.x, &s1.x);
  split2h(vals[1], &s0.y, &s1.y);
  split2h(vals[2], &s0.z, &s1.z);
  split2h(vals[3], &s0.w, &s1.w);
  size_t base = (size_t)row * DD + tid * 4;
  *(ushort4*)&o0[base] = s0;
  *(ushort4*)&o1[base] = s1;
}

// ---------------- fused transpose+split2 of all four attention weights ----------------
__global__ __launch_bounds__(256) void k_transpose_all(
    const float* __restrict__ wq, const float* __restrict__ wk,
    const float* __restrict__ wv, const float* __restrict__ wo,
    u16* __restrict__ wqt0, u16* __restrict__ wqt1,
    u16* __restrict__ wkt0, u16* __restrict__ wkt1,
    u16* __restrict__ wvt0, u16* __restrict__ wvt1,
    u16* __restrict__ wot0, u16* __restrict__ wot1) {
  int id = blockIdx.x;
  const float* Wm; u16 *T0, *T1; int K = 1024, N; int n0, k0;
  if (id < 256)      { Wm = wq; T0 = wqt0; T1 = wqt1; N = 1024; n0 = (id & 15) * 64; k0 = (id >> 4) * 64; }
  else if (id < 320) { int t = id - 256; Wm = wk; T0 = wkt0; T1 = wkt1; N = 256; n0 = (t & 3) * 64; k0 = (t >> 2) * 64; }
  else if (id < 384) { int t = id - 320; Wm = wv; T0 = wvt0; T1 = wvt1; N = 256; n0 = (t & 3) * 64; k0 = (t >> 2) * 64; }
  else               { int t = id - 384; Wm = wo; T0 = wot0; T1 = wot1; N = 1024; n0 = (t & 15) * 64; k0 = (t >> 4) * 64; }
  __shared__ float tile[64][65];
  int tc = threadIdx.x & 15, tr = threadIdx.x >> 4;
#pragma unroll
  for (int kk = 0; kk < 64; kk += 16) {
    float4 v = *(const float4*)&Wm[(size_t)(k0 + kk + tr) * N + n0 + tc * 4];
    tile[kk + tr][tc*4+0] = v.x; tile[kk + tr][tc*4+1] = v.y;
    tile[kk + tr][tc*4+2] = v.z; tile[kk + tr][tc*4+3] = v.w;
  }
  __syncthreads();
#pragma unroll
  for (int nn = 0; nn < 64; nn += 16) {
    int n = nn + tr;
    ushort4 s0, s1;
    split2h(tile[tc*4+0][n], &s0.x, &s1.x);
    split2h(tile[tc*4+1][n], &s0.y, &s1.y);
    split2h(tile[tc*4+2][n], &s0.z, &s1.z);
    split2h(tile[tc*4+3][n], &s0.w, &s1.w);
    size_t base = (size_t)(n0 + n) * K + k0 + tc * 4;
    *(ushort4*)&T0[base] = s0;
    *(ushort4*)&T1[base] = s1;
  }
}

// ======== split-2 fp16 GEMM body, gu skeleton: 128x64 tile, BK=32, pitch 56 ========
#define S2GEMM_BODY(a0p, a1p, b0p, b1p, KTOT) \
  __shared__ __align__(16) u16 A0s[128][56], A1s[128][56]; \
  __shared__ __align__(16) u16 B0s[64][56], B1s[64][56]; \
  int tid = threadIdx.x, lane = tid & 63, w = tid >> 6; \
  int wm = (w & 1) * 64, wn = (w >> 1) * 32; \
  int lr = lane & 15, lk = (lane >> 4) * 8; \
  int br = tid >> 2, bc = (tid & 3) * 8; \
  f32x4 accm[4][2] = {}, accx[4][2] = {}; \
  for (int k0 = 0; k0 < (KTOT); k0 += 32) { \
    uint4 a0v0 = *(const uint4*)((a0p) + (size_t)br * (KTOT) + k0 + bc); \
    uint4 a0v1 = *(const uint4*)((a0p) + (size_t)(64 + br) * (KTOT) + k0 + bc); \
    uint4 a1v0 = *(const uint4*)((a1p) + (size_t)br * (KTOT) + k0 + bc); \
    uint4 a1v1 = *(const uint4*)((a1p) + (size_t)(64 + br) * (KTOT) + k0 + bc); \
    uint4 b0v = *(const uint4*)((b0p) + (size_t)br * (KTOT) + k0 + bc); \
    uint4 b1v = *(const uint4*)((b1p) + (size_t)br * (KTOT) + k0 + bc); \
    __syncthreads(); \
    *(uint4*)&A0s[br][bc] = a0v0; \
    *(uint4*)&A0s[64 + br][bc] = a0v1; \
    *(uint4*)&A1s[br][bc] = a1v0; \
    *(uint4*)&A1s[64 + br][bc] = a1v1; \
    *(uint4*)&B0s[br][bc] = b0v; \
    *(uint4*)&B1s[br][bc] = b1v; \
    __syncthreads(); \
    f16x8 bq0[2], bq1[2]; \
    _Pragma("unroll") \
    for (int nf = 0; nf < 2; ++nf) { \
      bq0[nf] = ldh(&B0s[wn + nf*16 + lr][lk]); \
      bq1[nf] = ldh(&B1s[wn + nf*16 + lr][lk]); } \
    _Pragma("unroll") \
    for (int fm = 0; fm < 4; ++fm) { \
      f16x8 a0 = ldh(&A0s[wm + fm*16 + lr][lk]); \
      f16x8 a1 = ldh(&A1s[wm + fm*16 + lr][lk]); \
      _Pragma("unroll") \
      for (int nf = 0; nf < 2; ++nf) { \
        accm[fm][nf] = __builtin_amdgcn_mfma_f32_16x16x32_f16(a0, bq0[nf], accm[fm][nf], 0, 0, 0); \
        f32x4 cx = accx[fm][nf]; \
        cx = __builtin_amdgcn_mfma_f32_16x16x32_f16(a0, bq1[nf], cx, 0, 0, 0); \
        cx = __builtin_amdgcn_mfma_f32_16x16x32_f16(a1, bq0[nf], cx, 0, 0, 0); \
        accx[fm][nf] = cx; } } \
  }

// ---------------- fused QKV GEMM (split-2 fp16, gu skeleton) ----------------
__global__ __launch_bounds__(256) void k_qkv_s2(
    const u16* __restrict__ h0, const u16* __restrict__ h1,
    const u16* __restrict__ wqt0, const u16* __restrict__ wqt1,
    const u16* __restrict__ wkt0, const u16* __restrict__ wkt1,
    const u16* __restrict__ wvt0, const u16* __restrict__ wvt1,
    float* __restrict__ qb, float* __restrict__ kb, float* __restrict__ vb) {
  int nt = blockIdx.x, m0 = blockIdx.y * 128;
  const u16 *B0, *B1; float* Cm; int Nm, n0;
  if (nt < 16)      { B0 = wqt0; B1 = wqt1; Cm = qb; Nm = 1024; n0 = nt * 64; }
  else if (nt < 20) { B0 = wkt0; B1 = wkt1; Cm = kb; Nm = 256;  n0 = (nt - 16) * 64; }
  else              { B0 = wvt0; B1 = wvt1; Cm = vb; Nm = 256;  n0 = (nt - 20) * 64; }
  const u16* a0p = h0 + (size_t)m0 * 1024;
  const u16* a1p = h1 + (size_t)m0 * 1024;
  const u16* b0p = B0 + (size_t)n0 * 1024;
  const u16* b1p = B1 + (size_t)n0 * 1024;
  S2GEMM_BODY(a0p, a1p, b0p, b1p, 1024)
#pragma unroll
  for (int fm = 0; fm < 4; ++fm)
#pragma unroll
    for (int nf = 0; nf < 2; ++nf)
#pragma unroll
      for (int r = 0; r < 4; ++r) {
        int row = m0 + wm + fm*16 + (lane >> 4) * 4 + r;
        Cm[(size_t)row * Nm + n0 + wn + nf*16 + lr] = CVAL(fm, nf, r);
      }
}

// ---------------- per-head q/k rmsnorm + rope -> split-2 fp16 planes ----------------
__global__ __launch_bounds__(256) void k_qknorm_rope_split2(
    const float* __restrict__ qb, const float* __restrict__ kb,
    const float* __restrict__ qnw, const float* __restrict__ knw,
    const float* __restrict__ cosb, const float* __restrict__ sinb,
    u16* __restrict__ q0a, u16* __restrict__ q1a,
    u16* __restrict__ k0a, u16* __restrict__ k1a) {
  int tok = blockIdx.x, grp = blockIdx.y;
  int wv = threadIdx.x >> 6, d = threadIdx.x & 63;
  int s = tok & (SS - 1);
  const float* ptr; const float* wn;
  if (grp < 4) { ptr = qb + (size_t)tok * 1024 + (grp * 4 + wv) * 64; wn = qnw; }
  else         { ptr = kb + (size_t)tok * 256 + wv * 64;              wn = knw; }
  float v = ptr[d];
  float ssum = wred_sum(v * v);
  float rms = rsqrtf(ssum * (1.0f / 64.0f) + EPS_);
  float nv = v * rms * wn[d];
  float pn = __shfl_xor(nv, 32);
  float rot = (d < 32) ? -pn : pn;
  float val = nv * cosb[s * 64 + d] + rot * sinb[s * 64 + d];
  u16 a, b;
  split2h(val, &a, &b);
  if (grp < 4) {
    size_t idx = (size_t)tok * 1024 + (grp * 4 + wv) * 64 + d;
    q0a[idx] = a; q1a[idx] = b;
  } else {
    size_t idx = (size_t)tok * 256 + wv * 64 + d;
    k0a[idx] = a; k1a[idx] = b;
  }
}

// ---------------- v transpose + split2 ----------------
__global__ __launch_bounds__(256) void k_splitv2(const float* __restrict__ vb,
    u16* __restrict__ t0, u16* __restrict__ t1) {
  int k0 = blockIdx.x * 64, bkv = blockIdx.y;
  int b = bkv >> 2, kv = bkv & 3;
  __shared__ float tile[64][65];
  int tc = threadIdx.x & 15, tr = threadIdx.x >> 4;
#pragma unroll
  for (int kk = 0; kk < 64; kk += 16) {
    float4 v = *(const float4*)&vb[(size_t)(b * 1024 + k0 + kk + tr) * 256 + kv * 64 + tc * 4];
    tile[kk + tr][tc*4+0] = v.x; tile[kk + tr][tc*4+1] = v.y;
    tile[kk + tr][tc*4+2] = v.z; tile[kk + tr][tc*4+3] = v.w;
  }
  __syncthreads();
#pragma unroll
  for (int dd = 0; dd < 64; dd += 16) {
    int d = dd + tr;
    ushort4 s0, s1;
    split2h(tile[tc*4+0][d], &s0.x, &s1.x);
    split2h(tile[tc*4+1][d], &s0.y, &s1.y);
    split2h(tile[tc*4+2][d], &s0.z, &s1.z);
    split2h(tile[tc*4+3][d], &s0.w, &s1.w);
    size_t base = (size_t)(bkv * 64 + d) * 1024 + k0 + tc * 4;
    *(ushort4*)&t0[base] = s0;
    *(ushort4*)&t1[base] = s1;
  }
}

// ---------------- flash attention (paired) -> split-2 attn planes ----------------
__global__ __launch_bounds__(256) void k_flash(
    const u16* __restrict__ qs0, const u16* __restrict__ qs1,
    const u16* __restrict__ ks0, const u16* __restrict__ ks1,
    const u16* __restrict__ vt0, const u16* __restrict__ vt1,
    u16* __restrict__ at0, u16* __restrict__ at1) {
  int pair = blockIdx.x, bh = blockIdx.y;
  int b = bh >> 4, hh = bh & 15, kv = hh >> 2;
  int bkv = b * 4 + kv;
  __shared__ __align__(16) u16 Qs0[64*72], Qs1[64*72];
  __shared__ __align__(16) u16 Ks0[64*72], Ks1[64*72];
  __shared__ __align__(16) u16 Vs0[64*72], Vs1[64*72];
  __shared__ __align__(16) u16 Ps0[64*72], Ps1[64*72];
  int tid = threadIdx.x, lane = tid & 63, w = tid >> 6;
  int lr = lane & 15, g = lane >> 4;
  int wq0 = w * 16;
  const float c2 = 4.8828125e-4f;
#pragma unroll 1
  for (int half = 0; half < 2; ++half) {
    int qt = (half == 0) ? pair : (15 - pair);
    int q0 = qt * 64;
#pragma unroll
    for (int i = 0; i < 2; ++i) {
      int idx = tid + i * 256, r = idx >> 3, c = (idx & 7) * 8;
      size_t off = (size_t)(b * 1024 + q0 + r) * 1024 + hh * 64 + c;
      *(uint4*)&Qs0[r*72 + c] = *(const uint4*)(qs0 + off);
      *(uint4*)&Qs1[r*72 + c] = *(const uint4*)(qs1 + off);
    }
    f32x4 Om[4] = {}, Ox[4] = {};
    float mrow[4] = {-3.4e38f, -3.4e38f, -3.4e38f, -3.4e38f};
    float lrow[4] = {};
    __syncthreads();
    for (int kt = 0; kt <= qt; ++kt) {
      int k0 = kt * 64;
#pragma unroll
      for (int i = 0; i < 2; ++i) {
        int idx = tid + i * 256, r = idx >> 3, c = (idx & 7) * 8;
        size_t koff = (size_t)(b * 1024 + k0 + r) * 256 + kv * 64 + c;
        *(uint4*)&Ks0[r*72 + c] = *(const uint4*)(ks0 + koff);
        *(uint4*)&Ks1[r*72 + c] = *(const uint4*)(ks1 + koff);
        size_t voff = (size_t)(bkv * 64 + r) * 1024 + k0 + c;
        *(uint4*)&Vs0[r*72 + c] = *(const uint4*)(vt0 + voff);
        *(uint4*)&Vs1[r*72 + c] = *(const uint4*)(vt1 + voff);
      }
      __syncthreads();
      f32x4 Sm[4] = {}, Sx[4] = {};
#pragma unroll
      for (int ks = 0; ks < 2; ++ks) {
        f16x8 a0 = ldh(&Qs0[(wq0 + lr)*72 + ks*32 + g*8]);
        f16x8 a1 = ldh(&Qs1[(wq0 + lr)*72 + ks*32 + g*8]);
#pragma unroll
        for (int nt = 0; nt < 4; ++nt) {
          f16x8 b0 = ldh(&Ks0[(nt*16 + lr)*72 + ks*32 + g*8]);
          f16x8 b1 = ldh(&Ks1[(nt*16 + lr)*72 + ks*32 + g*8]);
          Sm[nt] = __builtin_amdgcn_mfma_f32_16x16x32_f16(a0, b0, Sm[nt], 0, 0, 0);
          f32x4 cx = Sx[nt];
          cx = __builtin_amdgcn_mfma_f32_16x16x32_f16(a0, b1, cx, 0, 0, 0);
          cx = __builtin_amdgcn_mfma_f32_16x16x32_f16(a1, b0, cx, 0, 0, 0);
          Sx[nt] = cx;
        }
      }
      bool diag = (kt == qt);
      float pvv[4][4], scl[4];
#pragma unroll
      for (int r = 0; r < 4; ++r) {
        int rowloc = wq0 + g*4 + r;
        float rm = -3.4e38f;
#pragma unroll
        for (int nt = 0; nt < 4; ++nt) {
          float s = (Sm[nt][r] + Sx[nt][r] * c2) * 0.125f;
          bool valid = (!diag) || (nt*16 + lr <= rowloc);
          s = valid ? s : -3.4e38f;
          pvv[r][nt] = s;
          rm = fmaxf(rm, s);
        }
#pragma unroll
        for (int o = 1; o < 16; o <<= 1) rm = fmaxf(rm, __shfl_xor(rm, o));
        float mn = fmaxf(mrow[r], rm);
        scl[r] = __expf(mrow[r] - mn);
        mrow[r] = mn;
        float rs = 0.f;
#pragma unroll
        for (int nt = 0; nt < 4; ++nt) {
          float p = (pvv[r][nt] > -3.0e38f) ? __expf(pvv[r][nt] - mn) : 0.f;
          pvv[r][nt] = p;
          rs += p;
        }
#pragma unroll
        for (int o = 1; o < 16; o <<= 1) rs += __shfl_xor(rs, o);
        lrow[r] = lrow[r] * scl[r] + rs;
      }
#pragma unroll
      for (int nt = 0; nt < 4; ++nt)
#pragma unroll
        for (int r = 0; r < 4; ++r) { Om[nt][r] *= scl[r]; Ox[nt][r] *= scl[r]; }
#pragma unroll
      for (int r = 0; r < 4; ++r)
#pragma unroll
        for (int nt = 0; nt < 4; ++nt) {
          u16 pa, pb;
          split2h(pvv[r][nt], &pa, &pb);
          int addr = (wq0 + g*4 + r)*72 + nt*16 + lr;
          Ps0[addr] = pa; Ps1[addr] = pb;
        }
#pragma unroll
      for (int ks = 0; ks < 2; ++ks) {
        f16x8 p0 = ldh(&Ps0[(wq0 + lr)*72 + ks*32 + g*8]);
        f16x8 p1 = ldh(&Ps1[(wq0 + lr)*72 + ks*32 + g*8]);
#pragma unroll
        for (int nt = 0; nt < 4; ++nt) {
          f16x8 v0 = ldh(&Vs0[(nt*16 + lr)*72 + ks*32 + g*8]);
          f16x8 v1 = ldh(&Vs1[(nt*16 + lr)*72 + ks*32 + g*8]);
          Om[nt] = __builtin_amdgcn_mfma_f32_16x16x32_f16(p0, v0, Om[nt], 0, 0, 0);
          f32x4 cx = Ox[nt];
          cx = __builtin_amdgcn_mfma_f32_16x16x32_f16(p0, v1, cx, 0, 0, 0);
          cx = __builtin_amdgcn_mfma_f32_16x16x32_f16(p1, v0, cx, 0, 0, 0);
          Ox[nt] = cx;
        }
      }
      __syncthreads();
    }
#pragma unroll
    for (int nt = 0; nt < 4; ++nt)
#pragma unroll
      for (int r = 0; r < 4; ++r) {
        float val = (Om[nt][r] + Ox[nt][r] * c2) / lrow[r];
        u16 sa, sb;
        split2h(val, &sa, &sb);
        size_t idx = (size_t)(b * 1024 + q0 + wq0 + g*4 + r) * 1024 + hh * 64 + nt*16 + lr;
        at0[idx] = sa; at1[idx] = sb;
      }
    __syncthreads();
  }
}

// ---------------- Wo GEMM + residual (split-2 fp16, gu skeleton) ----------------
__global__ __launch_bounds__(256) void k_wo_s2(
    const u16* __restrict__ at0, const u16* __restrict__ at1,
    const u16* __restrict__ wot0, const u16* __restrict__ wot1,
    const float* __restrict__ x, float* __restrict__ x2) {
  int n0 = blockIdx.x * 64, m0 = blockIdx.y * 128;
  const u16* a0p = at0 + (size_t)m0 * 1024;
  const u16* a1p = at1 + (size_t)m0 * 1024;
  const u16* b0p = wot0 + (size_t)n0 * 1024;
  const u16* b1p = wot1 + (size_t)n0 * 1024;
  S2GEMM_BODY(a0p, a1p, b0p, b1p, 1024)
#pragma unroll
  for (int fm = 0; fm < 4; ++fm)
#pragma unroll
    for (int nf = 0; nf < 2; ++nf)
#pragma unroll
      for (int r = 0; r < 4; ++r) {
        int row = m0 + wm + fm*16 + (lane >> 4) * 4 + r;
        int col = n0 + wn + nf*16 + lr;
        x2[(size_t)row * 1024 + col] = CVAL(fm, nf, r) + x[(size_t)row * 1024 + col];
      }
}

// ---------------- fused: rmsnorm(x2) -> tbh(bf16) + router logits (+ zero cnt/psum) ----------------
__global__ __launch_bounds__(256) void k_rmsnorm_logits(const float* __restrict__ x2,
    const float* __restrict__ w, const float* __restrict__ rw,
    u16* __restrict__ tbh, float* __restrict__ logits,
    int* __restrict__ cnt, float* __restrict__ psum) {
  int row = blockIdx.x, tid = threadIdx.x;
  if (row == 0 && tid < 16) { cnt[tid] = 0; psum[tid] = 0.f; }
  __shared__ __align__(16) float tl[1024];
  __shared__ float part[16][16];
  __shared__ float red[4];
  float4 v = ((const float4*)(x2 + (size_t)row * DD))[tid];
  float ss = v.x*v.x + v.y*v.y + v.z*v.z + v.w*v.w;
  ss = wred_sum(ss);
  if ((tid & 63) == 0) red[tid >> 6] = ss;
  __syncthreads();
  float tot = red[0] + red[1] + red[2] + red[3];
  float sc = rsqrtf(tot * (1.0f / DD) + EPS_);
  float4 wv = ((const float4*)w)[tid];
  float4 o = make_float4(v.x*sc*wv.x, v.y*sc*wv.y, v.z*sc*wv.z, v.w*sc*wv.w);
  ((float4*)tl)[tid] = o;
  ushort4 hb = make_ushort4(f2b(o.x), f2b(o.y), f2b(o.z), f2b(o.w));
  *(ushort4*)&tbh[(size_t)row * DD + tid * 4] = hb;
  __syncthreads();
  int e = tid & 15, ch = tid >> 4;
  float p = 0.f;
#pragma unroll 8
  for (int j = 0; j < 64; ++j) p = fmaf(tl[ch * 64 + j], rw[(ch * 64 + j) * EE + e], p);
  part[ch][e] = p;
  __syncthreads();
  if (tid < 16) {
    float s = 0.f;
#pragma unroll
    for (int c = 0; c < 16; ++c) s += part[c][tid];
    logits[(size_t)row * EE + tid] = s;
  }
}

// ---------------- route ----------------
__global__ __launch_bounds__(256) void k_route(const float* __restrict__ logits,
    int* __restrict__ cnt, int* __restrict__ listTok, int* __restrict__ tokslot,
    float* __restrict__ topw, float* __restrict__ psum) {
  int tid = threadIdx.x;
  int tok = blockIdx.x * 256 + tid;
  __shared__ int lcnt[16], gbase[16];
  __shared__ float lps[16];
  if (tid < 16) { lcnt[tid] = 0; lps[tid] = 0.f; }
  __syncthreads();
  float pr[16];
#pragma unroll
  for (int g = 0; g < 4; ++g) {
    float4 v = *(const float4*)&logits[(size_t)tok * EE + g * 4];
    pr[g*4+0] = v.x; pr[g*4+1] = v.y; pr[g*4+2] = v.z; pr[g*4+3] = v.w;
  }
  float mx = pr[0];
#pragma unroll
  for (int i = 1; i < 16; ++i) mx = fmaxf(mx, pr[i]);
  float s = 0.f;
#pragma unroll
  for (int i = 0; i < 16; ++i) { pr[i] = __expf(pr[i] - mx); s += pr[i]; }
  float inv = 1.0f / s;
#pragma unroll
  for (int i = 0; i < 16; ++i) pr[i] *= inv;
  int i1 = 0; float v1 = pr[0];
#pragma unroll
  for (int i = 1; i < 16; ++i) if (pr[i] > v1) { v1 = pr[i]; i1 = i; }
  int i2 = -1; float v2 = -1.f;
#pragma unroll
  for (int i = 0; i < 16; ++i) if (i != i1 && pr[i] > v2) { v2 = pr[i]; i2 = i; }
  float wsum = v1 + v2;
  int lp1 = atomicAdd(&lcnt[i1], 1);
  int lp2 = atomicAdd(&lcnt[i2], 1);
#pragma unroll
  for (int e = 0; e < 16; ++e) {
    float v = wred_sum(pr[e]);
    if ((tid & 63) == 0) atomicAdd(&lps[e], v);
  }
  __syncthreads();
  if (tid < 16) {
    gbase[tid] = atomicAdd(&cnt[tid], lcnt[tid]);
    atomicAdd(&psum[tid], lps[tid]);
  }
  __syncthreads();
  int p1 = gbase[i1] + lp1, p2 = gbase[i2] + lp2;
  listTok[i1 * 2048 + p1] = tok;
  listTok[i2 * 2048 + p2] = tok;
  tokslot[tok * 2 + 0] = i1 * 2048 + p1;
  tokslot[tok * 2 + 1] = i2 * 2048 + p2;
  topw[tok * 2 + 0] = v1 / wsum;
  topw[tok * 2 + 1] = v2 / wsum;
}

// ---------------- prefix + live-tile list (dense MoE grid) ----------------
__global__ void k_prefix(const int* __restrict__ cnt, int* __restrict__ offs,
                         int* __restrict__ tileE, int* __restrict__ tileM,
                         int* __restrict__ nTiles) {
  if (threadIdx.x == 0) {
    int s = 0, t = 0;
    for (int e = 0; e < 16; ++e) {
      offs[e] = s;
      for (int m0 = 0; m0 < cnt[e]; m0 += 128) { tileE[t] = e; tileM[t] = m0; ++t; }
      s += cnt[e];
    }
    nTiles[0] = t;
  }
}

// ---------------- MoE gate-or-up MFMA (z=0 gate, z=1 up; one weight panel per block) ----------------
__global__ __launch_bounds__(256) void k_gu1_mfma(const u16* __restrict__ tbh,
    const float* __restrict__ wg, const float* __restrict__ wu,
    const int* __restrict__ cnt, const int* __restrict__ offs,
    const int* __restrict__ listTok, const int* __restrict__ tileE,
    const int* __restrict__ tileM, const int* __restrict__ nTiles,
    float* __restrict__ gb, float* __restrict__ ub) {
  int ti = blockIdx.y;
  if (ti >= nTiles[0]) return;
  int e = tileE[ti];
  int ce = cnt[e];
  int m0 = tileM[ti];
  int n0 = blockIdx.x * 64;
  const float* wsrc = blockIdx.z ? wu : wg;
  float* outp = blockIdx.z ? ub : gb;
  __shared__ __align__(16) u16 Ah[128][56];
  __shared__ __align__(16) u16 Bh[64][56];
  __shared__ int rows[128];
  int tid = threadIdx.x;
  if (tid < 128) {
    int m = m0 + tid;
    rows[tid] = listTok[e * 2048 + (m < ce ? m : ce - 1)];
  }
  __syncthreads();
  int s_arow = tid >> 1, s_acol = (tid & 1) * 16;
  int s_nc = (tid & 31) * 2, s_kg = (tid >> 5) * 4;
  const float* wpe = wsrc + (size_t)e * DD * II + n0;
  const u16* ap = tbh + (size_t)rows[s_arow] * DD + s_acol;
  int lane = tid & 63, w = tid >> 6;
  int wm = (w & 1) * 64, wn = (w >> 1) * 32;
  int lr = lane & 15, lk = (lane >> 4) * 8;
  f32x4 acc[4][2] = {};
  for (int k0 = 0; k0 < DD; k0 += 32) {
    uint4 av0 = *(const uint4*)(ap + k0);
    uint4 av1 = *(const uint4*)(ap + k0 + 8);
    float2 b0 = *(const float2*)&wpe[(size_t)(k0 + s_kg + 0) * II + s_nc];
    float2 b1 = *(const float2*)&wpe[(size_t)(k0 + s_kg + 1) * II + s_nc];
    float2 b2 = *(const float2*)&wpe[(size_t)(k0 + s_kg + 2) * II + s_nc];
    float2 b3 = *(const float2*)&wpe[(size_t)(k0 + s_kg + 3) * II + s_nc];
    *(uint4*)&Ah[s_arow][s_acol]     = av0;
    *(uint4*)&Ah[s_arow][s_acol + 8] = av1;
    *(ushort4*)&Bh[s_nc][s_kg]     = make_ushort4(f2b(b0.x), f2b(b1.x), f2b(b2.x), f2b(b3.x));
    *(ushort4*)&Bh[s_nc + 1][s_kg] = make_ushort4(f2b(b0.y), f2b(b1.y), f2b(b2.y), f2b(b3.y));
    __syncthreads();
    bf16x8 af[4];
#pragma unroll
    for (int fm = 0; fm < 4; ++fm) af[fm] = ld_frag(&Ah[wm + fm*16 + lr][lk]);
#pragma unroll
    for (int nf = 0; nf < 2; ++nf) {
      bf16x8 bb = ld_frag(&Bh[wn + nf*16 + lr][lk]);
#pragma unroll
      for (int fm = 0; fm < 4; ++fm)
        acc[fm][nf] = __builtin_amdgcn_mfma_f32_16x16x32_bf16(af[fm], bb, acc[fm][nf], 0, 0, 0);
    }
    __syncthreads();
  }
  int ob = offs[e];
#pragma unroll
  for (int fm = 0; fm < 4; ++fm)
#pragma unroll
    for (int nf = 0; nf < 2; ++nf)
#pragma unroll
      for (int r = 0; r < 4; ++r) {
        int m = m0 + wm + fm*16 + (lane >> 4) * 4 + r;
        if (m < ce)
          outp[(size_t)(ob + m) * II + n0 + wn + nf*16 + (lane & 15)] = acc[fm][nf][r];
      }
}

// ---------------- silu(g)*u -> act (bf16), compact 4096xII ----------------
__global__ __launch_bounds__(256) void k_silu(const float* __restrict__ gb,
    const float* __restrict__ ub, u16* __restrict__ act, int n4) {
  int i = blockIdx.x * 256 + threadIdx.x;
  if (i < n4) {
    float4 g = ((const float4*)gb)[i];
    float4 u = ((const float4*)ub)[i];
    ushort4 o;
    o.x = f2b((g.x / (1.f + __expf(-g.x))) * u.x);
    o.y = f2b((g.y / (1.f + __expf(-g.y))) * u.y);
    o.z = f2b((g.z / (1.f + __expf(-g.z))) * u.z);
    o.w = f2b((g.w / (1.f + __expf(-g.w))) * u.w);
    ((ushort4*)act)[i] = o;
  }
}

// ---------------- MoE down MFMA (r13: grid x=n, y=tile) ----------------
__global__ __launch_bounds__(256) void k_down_mfma(const u16* __restrict__ act,
    const float* __restrict__ wd, const int* __restrict__ cnt, const int* __restrict__ offs,
    const int* __restrict__ tileE, const int* __restrict__ tileM,
    const int* __restrict__ nTiles, float* __restrict__ eo) {
  int ti = blockIdx.y;
  if (ti >= nTiles[0]) return;
  int e = tileE[ti];
  int ce = cnt[e];
  int m0 = tileM[ti];
  int n0 = blockIdx.x * 64;
  __shared__ __align__(16) u16 Ah[128][56];
  __shared__ __align__(16) u16 Bh[64][56];
  int tid = threadIdx.x;
  int ob = offs[e];
  int s_arow = tid >> 1, s_acol = (tid & 1) * 16;
  int s_nc = (tid & 31) * 2, s_kg = (tid >> 5) * 4;
  int mrow = m0 + s_arow; if (mrow >= ce) mrow = ce - 1;
  const u16* ap = act + (size_t)(ob + mrow) * II + s_acol;
  const float* wde = wd + (size_t)e * II * DD + n0;
  int lane = tid & 63, w = tid >> 6;
  int wm = (w & 1) * 64, wn = (w >> 1) * 32;
  int lr = lane & 15, lk = (lane >> 4) * 8;
  f32x4 acc[4][2] = {};
  for (int k0 = 0; k0 < II; k0 += 32) {
    uint4 av0 = *(const uint4*)(ap + k0);
    uint4 av1 = *(const uint4*)(ap + k0 + 8);
    float2 b0 = *(const float2*)&wde[(size_t)(k0 + s_kg + 0) * DD + s_nc];
    float2 b1 = *(const float2*)&wde[(size_t)(k0 + s_kg + 1) * DD + s_nc];
    float2 b2 = *(const float2*)&wde[(size_t)(k0 + s_kg + 2) * DD + s_nc];
    float2 b3 = *(const float2*)&wde[(size_t)(k0 + s_kg + 3) * DD + s_nc];
    *(uint4*)&Ah[s_arow][s_acol]     = av0;
    *(uint4*)&Ah[s_arow][s_acol + 8] = av1;
    *(ushort4*)&Bh[s_nc][s_kg]     = make_ushort4(f2b(b0.x), f2b(b1.x), f2b(b2.x), f2b(b3.x));
    *(ushort4*)&Bh[s_nc + 1][s_kg] = make_ushort4(f2b(b0.y), f2b(b1.y), f2b(b2.y), f2b(b3.y));
    __syncthreads();
    bf16x8 af[4];
#pragma unroll
    for (int fm = 0; fm < 4; ++fm) af[fm] = ld_frag(&Ah[wm + fm*16 + lr][lk]);
#pragma unroll
    for (int nf = 0; nf < 2; ++nf) {
      bf16x8 bb = ld_frag(&Bh[wn + nf*16 + lr][lk]);
#pragma unroll
      for (int fm = 0; fm < 4; ++fm)
        acc[fm][nf] = __builtin_amdgcn_mfma_f32_16x16x32_bf16(af[fm], bb, acc[fm][nf], 0, 0, 0);
    }
    __syncthreads();
  }
#pragma unroll
  for (int fm = 0; fm < 4; ++fm)
#pragma unroll
    for (int nf = 0; nf < 2; ++nf)
#pragma unroll
      for (int r = 0; r < 4; ++r) {
        int m = m0 + wm + fm*16 + (lane >> 4) * 4 + r;
        if (m < ce)
          eo[(size_t)(ob + m) * DD + n0 + wn + nf*16 + (lane & 15)] = acc[fm][nf][r];
      }
}

// ---------------- final combine (+ aux in block 0) ----------------
__global__ __launch_bounds__(256) void k_final(const float* __restrict__ x2,
    const float* __restrict__ eo, const int* __restrict__ tokslot,
    const float* __restrict__ topw, const int* __restrict__ offs,
    const int* __restrict__ cnt, const float* __restrict__ psum,
    float* __restrict__ out) {
  int tok = blockIdx.x, tid = threadIdx.x;
  int c0 = tokslot[tok * 2], c1 = tokslot[tok * 2 + 1];
  int s0 = offs[c0 >> 11] + (c0 & 2047);
  int s1 = offs[c1 >> 11] + (c1 & 2047);
  float w0 = topw[tok * 2], w1 = topw[tok * 2 + 1];
  float4 a = ((const float4*)(x2 + (size_t)tok * DD))[tid];
  float4 e0 = ((const float4*)(eo + (size_t)s0 * DD))[tid];
  float4 e1 = ((const float4*)(eo + (size_t)s1 * DD))[tid];
  float4 o = make_float4(a.x + w0*e0.x + w1*e1.x, a.y + w0*e0.y + w1*e1.y,
                         a.z + w0*e0.z + w1*e1.z, a.w + w0*e0.w + w1*e1.w);
  ((float4*)(out + (size_t)tok * DD))[tid] = o;
  if (tok == 0 && tid == 0) {
    float acc = 0.f;
    for (int e = 0; e < 16; ++e)
      acc += ((float)cnt[e] * (1.0f / 4096.0f)) * (psum[e] * (1.0f / 2048.0f));
    out[(size_t)TT * DD] = 16.0f * acc;
  }
}

extern "C" void kernel_launch(void* const* d_in, const int* in_sizes, int n_in,
                              void* d_out, int out_size, void* d_ws, size_t ws_size,
                              hipStream_t stream) {
  const float* x    = (const float*)d_in[0];
  const float* cosb = (const float*)d_in[1];
  const float* sinb = (const float*)d_in[2];
  const float* ln1w = (const float*)d_in[3];
  const float* wq   = (const float*)d_in[4];
  const float* wk   = (const float*)d_in[5];
  const float* wv   = (const float*)d_in[6];
  const float* wo   = (const float*)d_in[7];
  const float* qnw  = (const float*)d_in[8];
  const float* knw  = (const float*)d_in[9];
  const float* ln2w = (const float*)d_in[10];
  const float* rw   = (const float*)d_in[11];
  const float* wg   = (const float*)d_in[12];
  const float* wu   = (const float*)d_in[13];
  const float* wd   = (const float*)d_in[14];
  float* out = (float*)d_out;

  float* W = (float*)d_ws;
  int*   cnt     = (int*)W;
  int*   offs    = (int*)(W + 16);
  float* psum    = W + 32;
  int*   tokslot = (int*)(W + 64);
  float* topw    = W + 4160;
  int*   listTok = (int*)(W + 8256);
  float* logits  = W + 41024;
  int*   tileE   = (int*)(W + 73728);
  int*   tileM   = (int*)(W + 73792);
  int*   nTiles  = (int*)(W + 73856);
  size_t o = 81920;
#define ALLOC_F(name, n)   float* name = W + o; o += (n);
#define ALLOC_U16(name, n) u16* name = (u16*)(W + o); o += ((size_t)(n) + 1) / 2;
  ALLOC_U16(h0, 2097152) ALLOC_U16(h1, 2097152)
  ALLOC_F(qb, 2097152) ALLOC_F(kb, 524288) ALLOC_F(vb, 524288)
  ALLOC_U16(wqt0, 1048576) ALLOC_U16(wqt1, 1048576)
  ALLOC_U16(wkt0, 262144) ALLOC_U16(wkt1, 262144)
  ALLOC_U16(wvt0, 262144) ALLOC_U16(wvt1, 262144)
  ALLOC_U16(wot0, 1048576) ALLOC_U16(wot1, 1048576)
  ALLOC_U16(qs0, 2097152) ALLOC_U16(qs1, 2097152)
  ALLOC_U16(ks0, 524288) ALLOC_U16(ks1, 524288)
  ALLOC_U16(vt0, 524288) ALLOC_U16(vt1, 524288)
  ALLOC_U16(at0, 2097152) ALLOC_U16(at1, 2097152)
  ALLOC_F(x2, 2097152)
  ALLOC_U16(tbh, 2097152)
  ALLOC_U16(act, 5767168)
  ALLOC_F(eo, 4194304)
  ALLOC_F(gb, 5767168)
  ALLOC_F(ub, 5767168)
#undef ALLOC_F
#undef ALLOC_U16

  k_rmsnorm_split2<<<TT, 256, 0, stream>>>(x, ln1w, h0, h1);
  k_transpose_all<<<640, 256, 0, stream>>>(wq, wk, wv, wo,
      wqt0, wqt1, wkt0, wkt1, wvt0, wvt1, wot0, wot1);
  k_qkv_s2<<<dim3(24, 16), 256, 0, stream>>>(h0, h1,
      wqt0, wqt1, wkt0, wkt1, wvt0, wvt1, qb, kb, vb);
  k_qknorm_rope_split2<<<dim3(TT, 5), 256, 0, stream>>>(qb, kb, qnw, knw, cosb, sinb,
      qs0, qs1, ks0, ks1);
  k_splitv2<<<dim3(16, 8), 256, 0, stream>>>(vb, vt0, vt1);
  k_flash<<<dim3(8, 32), 256, 0, stream>>>(qs0, qs1, ks0, ks1, vt0, vt1, at0, at1);
  k_wo_s2<<<dim3(16, 16), 256, 0, stream>>>(at0, at1, wot0, wot1, x, x2);
  k_rmsnorm_logits<<<TT, 256, 0, stream>>>(x2, ln2w, rw, tbh, logits, cnt, psum);
  k_route<<<TT / 256, 256, 0, stream>>>(logits, cnt, listTok, tokslot, topw, psum);
  k_prefix<<<1, 1, 0, stream>>>(cnt, offs, tileE, tileM, nTiles);
  k_gu1_mfma<<<dim3(22, 48, 2), 256, 0, stream>>>(tbh, wg, wu, cnt, offs, listTok,
      tileE, tileM, nTiles, gb, ub);
  k_silu<<<(4096 * II / 4 + 255) / 256, 256, 0, stream>>>(gb, ub, act, 4096 * II / 4);
  k_down_mfma<<<dim3(16, 48), 256, 0, stream>>>(act, wd, cnt, offs,
      tileE, tileM, nTiles, eo);
  k_final<<<TT, 256, 0, stream>>>(x2, eo, tokslot, topw, offs, cnt, psum, out);
}

// Round 17
// 354.745 us; speedup vs baseline: 1.0418x; 1.0418x over previous
//
#include <hip/hip_runtime.h>

#define BB 2
#define SS 1024
#define DD 1024
#define HH 16
#define KVH 4
#define HDD 64
#define EE 16
#define II 1408
#define TT (BB*SS)
#define EPS_ 1e-6f

typedef unsigned short u16;
typedef __bf16 bf16x8 __attribute__((ext_vector_type(8)));
typedef _Float16 f16x8 __attribute__((ext_vector_type(8)));
typedef float f32x4 __attribute__((ext_vector_type(4)));

__device__ __forceinline__ float wred_sum(float v) {
#pragma unroll
  for (int o = 32; o > 0; o >>= 1) v += __shfl_xor(v, o);
  return v;
}

__device__ __forceinline__ u16 f2b(float f) {
  __bf16 h = (__bf16)f;
  return __builtin_bit_cast(u16, h);
}

__device__ __forceinline__ bf16x8 ld_frag(const u16* p) {
  return __builtin_bit_cast(bf16x8, *(const uint4*)p);
}
__device__ __forceinline__ f16x8 ldh(const u16* p) {
  return __builtin_bit_cast(f16x8, *(const uint4*)p);
}

// fp16 split-2 with scaled residual: v ~= h0 + h1 * 2^-11 (error ~2^-22)
__device__ __forceinline__ void split2h(float v, u16* o0, u16* o1) {
  _Float16 a = (_Float16)v;
  float fa = (float)a;
  _Float16 b = (_Float16)((v - fa) * 2048.0f);
  *o0 = __builtin_bit_cast(u16, a);
  *o1 = __builtin_bit_cast(u16, b);
}

#define CVAL(fm, nf, r) (accm[fm][nf][r] + accx[fm][nf][r] * 4.8828125e-4f)

// ---------------- rmsnorm with split-2 fp16 output ----------------
__global__ __launch_bounds__(256) void k_rmsnorm_split2(const float* __restrict__ x,
    const float* __restrict__ w, u16* __restrict__ o0, u16* __restrict__ o1) {
  int row = blockIdx.x, tid = threadIdx.x;
  float4 v = ((const float4*)(x + (size_t)row * DD))[tid];
  float ss = v.x*v.x + v.y*v.y + v.z*v.z + v.w*v.w;
  ss = wred_sum(ss);
  __shared__ float red[4];
  if ((tid & 63) == 0) red[tid >> 6] = ss;
  __syncthreads();
  float tot = red[0] + red[1] + red[2] + red[3];
  float sc = rsqrtf(tot * (1.0f / DD) + EPS_);
  float4 wv = ((const float4*)w)[tid];
  float vals[4] = {v.x*sc*wv.x, v.y*sc*wv.y, v.z*sc*wv.z, v.w*sc*wv.w};
  ushort4 s0, s1;
  split2h(vals[0], &s0.x, &s1.x);
  split2h(vals[1], &s0.y, &s1.y);
  split2h(vals[2], &s0.z, &s1.z);
  split2h(vals[3], &s0.w, &s1.w);
  size_t base = (size_t)row * DD + tid * 4;
  *(ushort4*)&o0[base] = s0;
  *(ushort4*)&o1[base] = s1;
}

// ---------------- fused transpose+split2 of all four attention weights ----------------
__global__ __launch_bounds__(256) void k_transpose_all(
    const float* __restrict__ wq, const float* __restrict__ wk,
    const float* __restrict__ wv, const float* __restrict__ wo,
    u16* __restrict__ wqt0, u16* __restrict__ wqt1,
    u16* __restrict__ wkt0, u16* __restrict__ wkt1,
    u16* __restrict__ wvt0, u16* __restrict__ wvt1,
    u16* __restrict__ wot0, u16* __restrict__ wot1) {
  int id = blockIdx.x;
  const float* Wm; u16 *T0, *T1; int K = 1024, N; int n0, k0;
  if (id < 256)      { Wm = wq; T0 = wqt0; T1 = wqt1; N = 1024; n0 = (id & 15) * 64; k0 = (id >> 4) * 64; }
  else if (id < 320) { int t = id - 256; Wm = wk; T0 = wkt0; T1 = wkt1; N = 256; n0 = (t & 3) * 64; k0 = (t >> 2) * 64; }
  else if (id < 384) { int t = id - 320; Wm = wv; T0 = wvt0; T1 = wvt1; N = 256; n0 = (t & 3) * 64; k0 = (t >> 2) * 64; }
  else               { int t = id - 384; Wm = wo; T0 = wot0; T1 = wot1; N = 1024; n0 = (t & 15) * 64; k0 = (t >> 4) * 64; }
  __shared__ float tile[64][65];
  int tc = threadIdx.x & 15, tr = threadIdx.x >> 4;
#pragma unroll
  for (int kk = 0; kk < 64; kk += 16) {
    float4 v = *(const float4*)&Wm[(size_t)(k0 + kk + tr) * N + n0 + tc * 4];
    tile[kk + tr][tc*4+0] = v.x; tile[kk + tr][tc*4+1] = v.y;
    tile[kk + tr][tc*4+2] = v.z; tile[kk + tr][tc*4+3] = v.w;
  }
  __syncthreads();
#pragma unroll
  for (int nn = 0; nn < 64; nn += 16) {
    int n = nn + tr;
    ushort4 s0, s1;
    split2h(tile[tc*4+0][n], &s0.x, &s1.x);
    split2h(tile[tc*4+1][n], &s0.y, &s1.y);
    split2h(tile[tc*4+2][n], &s0.z, &s1.z);
    split2h(tile[tc*4+3][n], &s0.w, &s1.w);
    size_t base = (size_t)(n0 + n) * K + k0 + tc * 4;
    *(ushort4*)&T0[base] = s0;
    *(ushort4*)&T1[base] = s1;
  }
}

// ======== split-2 fp16 GEMM body, gu skeleton: 128x64 tile, BK=32, pitch 56 ========
#define S2GEMM_BODY(a0p, a1p, b0p, b1p, KTOT) \
  __shared__ __align__(16) u16 A0s[128][56], A1s[128][56]; \
  __shared__ __align__(16) u16 B0s[64][56], B1s[64][56]; \
  int tid = threadIdx.x, lane = tid & 63, w = tid >> 6; \
  int wm = (w & 1) * 64, wn = (w >> 1) * 32; \
  int lr = lane & 15, lk = (lane >> 4) * 8; \
  int br = tid >> 2, bc = (tid & 3) * 8; \
  f32x4 accm[4][2] = {}, accx[4][2] = {}; \
  for (int k0 = 0; k0 < (KTOT); k0 += 32) { \
    uint4 a0v0 = *(const uint4*)((a0p) + (size_t)br * (KTOT) + k0 + bc); \
    uint4 a0v1 = *(const uint4*)((a0p) + (size_t)(64 + br) * (KTOT) + k0 + bc); \
    uint4 a1v0 = *(const uint4*)((a1p) + (size_t)br * (KTOT) + k0 + bc); \
    uint4 a1v1 = *(const uint4*)((a1p) + (size_t)(64 + br) * (KTOT) + k0 + bc); \
    uint4 b0v = *(const uint4*)((b0p) + (size_t)br * (KTOT) + k0 + bc); \
    uint4 b1v = *(const uint4*)((b1p) + (size_t)br * (KTOT) + k0 + bc); \
    __syncthreads(); \
    *(uint4*)&A0s[br][bc] = a0v0; \
    *(uint4*)&A0s[64 + br][bc] = a0v1; \
    *(uint4*)&A1s[br][bc] = a1v0; \
    *(uint4*)&A1s[64 + br][bc] = a1v1; \
    *(uint4*)&B0s[br][bc] = b0v; \
    *(uint4*)&B1s[br][bc] = b1v; \
    __syncthreads(); \
    f16x8 bq0[2], bq1[2]; \
    _Pragma("unroll") \
    for (int nf = 0; nf < 2; ++nf) { \
      bq0[nf] = ldh(&B0s[wn + nf*16 + lr][lk]); \
      bq1[nf] = ldh(&B1s[wn + nf*16 + lr][lk]); } \
    _Pragma("unroll") \
    for (int fm = 0; fm < 4; ++fm) { \
      f16x8 a0 = ldh(&A0s[wm + fm*16 + lr][lk]); \
      f16x8 a1 = ldh(&A1s[wm + fm*16 + lr][lk]); \
      _Pragma("unroll") \
      for (int nf = 0; nf < 2; ++nf) { \
        accm[fm][nf] = __builtin_amdgcn_mfma_f32_16x16x32_f16(a0, bq0[nf], accm[fm][nf], 0, 0, 0); \
        f32x4 cx = accx[fm][nf]; \
        cx = __builtin_amdgcn_mfma_f32_16x16x32_f16(a0, bq1[nf], cx, 0, 0, 0); \
        cx = __builtin_amdgcn_mfma_f32_16x16x32_f16(a1, bq0[nf], cx, 0, 0, 0); \
        accx[fm][nf] = cx; } } \
  }

// ---------------- fused QKV GEMM (split-2 fp16, gu skeleton) ----------------
__global__ __launch_bounds__(256) void k_qkv_s2(
    const u16* __restrict__ h0, const u16* __restrict__ h1,
    const u16* __restrict__ wqt0, const u16* __restrict__ wqt1,
    const u16* __restrict__ wkt0, const u16* __restrict__ wkt1,
    const u16* __restrict__ wvt0, const u16* __restrict__ wvt1,
    float* __restrict__ qb, float* __restrict__ kb, float* __restrict__ vb) {
  int nt = blockIdx.x, m0 = blockIdx.y * 128;
  const u16 *B0, *B1; float* Cm; int Nm, n0;
  if (nt < 16)      { B0 = wqt0; B1 = wqt1; Cm = qb; Nm = 1024; n0 = nt * 64; }
  else if (nt < 20) { B0 = wkt0; B1 = wkt1; Cm = kb; Nm = 256;  n0 = (nt - 16) * 64; }
  else              { B0 = wvt0; B1 = wvt1; Cm = vb; Nm = 256;  n0 = (nt - 20) * 64; }
  const u16* a0p = h0 + (size_t)m0 * 1024;
  const u16* a1p = h1 + (size_t)m0 * 1024;
  const u16* b0p = B0 + (size_t)n0 * 1024;
  const u16* b1p = B1 + (size_t)n0 * 1024;
  S2GEMM_BODY(a0p, a1p, b0p, b1p, 1024)
#pragma unroll
  for (int fm = 0; fm < 4; ++fm)
#pragma unroll
    for (int nf = 0; nf < 2; ++nf)
#pragma unroll
      for (int r = 0; r < 4; ++r) {
        int row = m0 + wm + fm*16 + (lane >> 4) * 4 + r;
        Cm[(size_t)row * Nm + n0 + wn + nf*16 + lr] = CVAL(fm, nf, r);
      }
}

// ---------------- per-head q/k rmsnorm + rope -> split-2 fp16 planes ----------------
__global__ __launch_bounds__(256) void k_qknorm_rope_split2(
    const float* __restrict__ qb, const float* __restrict__ kb,
    const float* __restrict__ qnw, const float* __restrict__ knw,
    const float* __restrict__ cosb, const float* __restrict__ sinb,
    u16* __restrict__ q0a, u16* __restrict__ q1a,
    u16* __restrict__ k0a, u16* __restrict__ k1a) {
  int tok = blockIdx.x, grp = blockIdx.y;
  int wv = threadIdx.x >> 6, d = threadIdx.x & 63;
  int s = tok & (SS - 1);
  const float* ptr; const float* wn;
  if (grp < 4) { ptr = qb + (size_t)tok * 1024 + (grp * 4 + wv) * 64; wn = qnw; }
  else         { ptr = kb + (size_t)tok * 256 + wv * 64;              wn = knw; }
  float v = ptr[d];
  float ssum = wred_sum(v * v);
  float rms = rsqrtf(ssum * (1.0f / 64.0f) + EPS_);
  float nv = v * rms * wn[d];
  float pn = __shfl_xor(nv, 32);
  float rot = (d < 32) ? -pn : pn;
  float val = nv * cosb[s * 64 + d] + rot * sinb[s * 64 + d];
  u16 a, b;
  split2h(val, &a, &b);
  if (grp < 4) {
    size_t idx = (size_t)tok * 1024 + (grp * 4 + wv) * 64 + d;
    q0a[idx] = a; q1a[idx] = b;
  } else {
    size_t idx = (size_t)tok * 256 + wv * 64 + d;
    k0a[idx] = a; k1a[idx] = b;
  }
}

// ---------------- v transpose + split2 ----------------
__global__ __launch_bounds__(256) void k_splitv2(const float* __restrict__ vb,
    u16* __restrict__ t0, u16* __restrict__ t1) {
  int k0 = blockIdx.x * 64, bkv = blockIdx.y;
  int b = bkv >> 2, kv = bkv & 3;
  __shared__ float tile[64][65];
  int tc = threadIdx.x & 15, tr = threadIdx.x >> 4;
#pragma unroll
  for (int kk = 0; kk < 64; kk += 16) {
    float4 v = *(const float4*)&vb[(size_t)(b * 1024 + k0 + kk + tr) * 256 + kv * 64 + tc * 4];
    tile[kk + tr][tc*4+0] = v.x; tile[kk + tr][tc*4+1] = v.y;
    tile[kk + tr][tc*4+2] = v.z; tile[kk + tr][tc*4+3] = v.w;
  }
  __syncthreads();
#pragma unroll
  for (int dd = 0; dd < 64; dd += 16) {
    int d = dd + tr;
    ushort4 s0, s1;
    split2h(tile[tc*4+0][d], &s0.x, &s1.x);
    split2h(tile[tc*4+1][d], &s0.y, &s1.y);
    split2h(tile[tc*4+2][d], &s0.z, &s1.z);
    split2h(tile[tc*4+3][d], &s0.w, &s1.w);
    size_t base = (size_t)(bkv * 64 + d) * 1024 + k0 + tc * 4;
    *(ushort4*)&t0[base] = s0;
    *(ushort4*)&t1[base] = s1;
  }
}

// ---------------- flash attention (paired) -> split-2 attn planes ----------------
__global__ __launch_bounds__(256) void k_flash(
    const u16* __restrict__ qs0, const u16* __restrict__ qs1,
    const u16* __restrict__ ks0, const u16* __restrict__ ks1,
    const u16* __restrict__ vt0, const u16* __restrict__ vt1,
    u16* __restrict__ at0, u16* __restrict__ at1) {
  int pair = blockIdx.x, bh = blockIdx.y;
  int b = bh >> 4, hh = bh & 15, kv = hh >> 2;
  int bkv = b * 4 + kv;
  __shared__ __align__(16) u16 Qs0[64*72], Qs1[64*72];
  __shared__ __align__(16) u16 Ks0[64*72], Ks1[64*72];
  __shared__ __align__(16) u16 Vs0[64*72], Vs1[64*72];
  __shared__ __align__(16) u16 Ps0[64*72], Ps1[64*72];
  int tid = threadIdx.x, lane = tid & 63, w = tid >> 6;
  int lr = lane & 15, g = lane >> 4;
  int wq0 = w * 16;
  const float c2 = 4.8828125e-4f;
#pragma unroll 1
  for (int half = 0; half < 2; ++half) {
    int qt = (half == 0) ? pair : (15 - pair);
    int q0 = qt * 64;
#pragma unroll
    for (int i = 0; i < 2; ++i) {
      int idx = tid + i * 256, r = idx >> 3, c = (idx & 7) * 8;
      size_t off = (size_t)(b * 1024 + q0 + r) * 1024 + hh * 64 + c;
      *(uint4*)&Qs0[r*72 + c] = *(const uint4*)(qs0 + off);
      *(uint4*)&Qs1[r*72 + c] = *(const uint4*)(qs1 + off);
    }
    f32x4 Om[4] = {}, Ox[4] = {};
    float mrow[4] = {-3.4e38f, -3.4e38f, -3.4e38f, -3.4e38f};
    float lrow[4] = {};
    __syncthreads();
    for (int kt = 0; kt <= qt; ++kt) {
      int k0 = kt * 64;
#pragma unroll
      for (int i = 0; i < 2; ++i) {
        int idx = tid + i * 256, r = idx >> 3, c = (idx & 7) * 8;
        size_t koff = (size_t)(b * 1024 + k0 + r) * 256 + kv * 64 + c;
        *(uint4*)&Ks0[r*72 + c] = *(const uint4*)(ks0 + koff);
        *(uint4*)&Ks1[r*72 + c] = *(const uint4*)(ks1 + koff);
        size_t voff = (size_t)(bkv * 64 + r) * 1024 + k0 + c;
        *(uint4*)&Vs0[r*72 + c] = *(const uint4*)(vt0 + voff);
        *(uint4*)&Vs1[r*72 + c] = *(const uint4*)(vt1 + voff);
      }
      __syncthreads();
      f32x4 Sm[4] = {}, Sx[4] = {};
#pragma unroll
      for (int ks = 0; ks < 2; ++ks) {
        f16x8 a0 = ldh(&Qs0[(wq0 + lr)*72 + ks*32 + g*8]);
        f16x8 a1 = ldh(&Qs1[(wq0 + lr)*72 + ks*32 + g*8]);
#pragma unroll
        for (int nt = 0; nt < 4; ++nt) {
          f16x8 b0 = ldh(&Ks0[(nt*16 + lr)*72 + ks*32 + g*8]);
          f16x8 b1 = ldh(&Ks1[(nt*16 + lr)*72 + ks*32 + g*8]);
          Sm[nt] = __builtin_amdgcn_mfma_f32_16x16x32_f16(a0, b0, Sm[nt], 0, 0, 0);
          f32x4 cx = Sx[nt];
          cx = __builtin_amdgcn_mfma_f32_16x16x32_f16(a0, b1, cx, 0, 0, 0);
          cx = __builtin_amdgcn_mfma_f32_16x16x32_f16(a1, b0, cx, 0, 0, 0);
          Sx[nt] = cx;
        }
      }
      bool diag = (kt == qt);
      float pvv[4][4], scl[4];
#pragma unroll
      for (int r = 0; r < 4; ++r) {
        int rowloc = wq0 + g*4 + r;
        float rm = -3.4e38f;
#pragma unroll
        for (int nt = 0; nt < 4; ++nt) {
          float s = (Sm[nt][r] + Sx[nt][r] * c2) * 0.125f;
          bool valid = (!diag) || (nt*16 + lr <= rowloc);
          s = valid ? s : -3.4e38f;
          pvv[r][nt] = s;
          rm = fmaxf(rm, s);
        }
#pragma unroll
        for (int o = 1; o < 16; o <<= 1) rm = fmaxf(rm, __shfl_xor(rm, o));
        float mn = fmaxf(mrow[r], rm);
        scl[r] = __expf(mrow[r] - mn);
        mrow[r] = mn;
        float rs = 0.f;
#pragma unroll
        for (int nt = 0; nt < 4; ++nt) {
          float p = (pvv[r][nt] > -3.0e38f) ? __expf(pvv[r][nt] - mn) : 0.f;
          pvv[r][nt] = p;
          rs += p;
        }
#pragma unroll
        for (int o = 1; o < 16; o <<= 1) rs += __shfl_xor(rs, o);
        lrow[r] = lrow[r] * scl[r] + rs;
      }
#pragma unroll
      for (int nt = 0; nt < 4; ++nt)
#pragma unroll
        for (int r = 0; r < 4; ++r) { Om[nt][r] *= scl[r]; Ox[nt][r] *= scl[r]; }
#pragma unroll
      for (int r = 0; r < 4; ++r)
#pragma unroll
        for (int nt = 0; nt < 4; ++nt) {
          u16 pa, pb;
          split2h(pvv[r][nt], &pa, &pb);
          int addr = (wq0 + g*4 + r)*72 + nt*16 + lr;
          Ps0[addr] = pa; Ps1[addr] = pb;
        }
#pragma unroll
      for (int ks = 0; ks < 2; ++ks) {
        f16x8 p0 = ldh(&Ps0[(wq0 + lr)*72 + ks*32 + g*8]);
        f16x8 p1 = ldh(&Ps1[(wq0 + lr)*72 + ks*32 + g*8]);
#pragma unroll
        for (int nt = 0; nt < 4; ++nt) {
          f16x8 v0 = ldh(&Vs0[(nt*16 + lr)*72 + ks*32 + g*8]);
          f16x8 v1 = ldh(&Vs1[(nt*16 + lr)*72 + ks*32 + g*8]);
          Om[nt] = __builtin_amdgcn_mfma_f32_16x16x32_f16(p0, v0, Om[nt], 0, 0, 0);
          f32x4 cx = Ox[nt];
          cx = __builtin_amdgcn_mfma_f32_16x16x32_f16(p0, v1, cx, 0, 0, 0);
          cx = __builtin_amdgcn_mfma_f32_16x16x32_f16(p1, v0, cx, 0, 0, 0);
          Ox[nt] = cx;
        }
      }
      __syncthreads();
    }
#pragma unroll
    for (int nt = 0; nt < 4; ++nt)
#pragma unroll
      for (int r = 0; r < 4; ++r) {
        float val = (Om[nt][r] + Ox[nt][r] * c2) / lrow[r];
        u16 sa, sb;
        split2h(val, &sa, &sb);
        size_t idx = (size_t)(b * 1024 + q0 + wq0 + g*4 + r) * 1024 + hh * 64 + nt*16 + lr;
        at0[idx] = sa; at1[idx] = sb;
      }
    __syncthreads();
  }
}

// ---------------- Wo GEMM + residual (split-2 fp16, gu skeleton) ----------------
__global__ __launch_bounds__(256) void k_wo_s2(
    const u16* __restrict__ at0, const u16* __restrict__ at1,
    const u16* __restrict__ wot0, const u16* __restrict__ wot1,
    const float* __restrict__ x, float* __restrict__ x2) {
  int n0 = blockIdx.x * 64, m0 = blockIdx.y * 128;
  const u16* a0p = at0 + (size_t)m0 * 1024;
  const u16* a1p = at1 + (size_t)m0 * 1024;
  const u16* b0p = wot0 + (size_t)n0 * 1024;
  const u16* b1p = wot1 + (size_t)n0 * 1024;
  S2GEMM_BODY(a0p, a1p, b0p, b1p, 1024)
#pragma unroll
  for (int fm = 0; fm < 4; ++fm)
#pragma unroll
    for (int nf = 0; nf < 2; ++nf)
#pragma unroll
      for (int r = 0; r < 4; ++r) {
        int row = m0 + wm + fm*16 + (lane >> 4) * 4 + r;
        int col = n0 + wn + nf*16 + lr;
        x2[(size_t)row * 1024 + col] = CVAL(fm, nf, r) + x[(size_t)row * 1024 + col];
      }
}

// ---------------- fused: rmsnorm(x2) -> tbh(bf16) + router logits (+ zero cnt/psum) ----------------
__global__ __launch_bounds__(256) void k_rmsnorm_logits(const float* __restrict__ x2,
    const float* __restrict__ w, const float* __restrict__ rw,
    u16* __restrict__ tbh, float* __restrict__ logits,
    int* __restrict__ cnt, float* __restrict__ psum) {
  int row = blockIdx.x, tid = threadIdx.x;
  if (row == 0 && tid < 16) { cnt[tid] = 0; psum[tid] = 0.f; }
  __shared__ __align__(16) float tl[1024];
  __shared__ float part[16][16];
  __shared__ float red[4];
  float4 v = ((const float4*)(x2 + (size_t)row * DD))[tid];
  float ss = v.x*v.x + v.y*v.y + v.z*v.z + v.w*v.w;
  ss = wred_sum(ss);
  if ((tid & 63) == 0) red[tid >> 6] = ss;
  __syncthreads();
  float tot = red[0] + red[1] + red[2] + red[3];
  float sc = rsqrtf(tot * (1.0f / DD) + EPS_);
  float4 wv = ((const float4*)w)[tid];
  float4 o = make_float4(v.x*sc*wv.x, v.y*sc*wv.y, v.z*sc*wv.z, v.w*sc*wv.w);
  ((float4*)tl)[tid] = o;
  ushort4 hb = make_ushort4(f2b(o.x), f2b(o.y), f2b(o.z), f2b(o.w));
  *(ushort4*)&tbh[(size_t)row * DD + tid * 4] = hb;
  __syncthreads();
  int e = tid & 15, ch = tid >> 4;
  float p = 0.f;
#pragma unroll 8
  for (int j = 0; j < 64; ++j) p = fmaf(tl[ch * 64 + j], rw[(ch * 64 + j) * EE + e], p);
  part[ch][e] = p;
  __syncthreads();
  if (tid < 16) {
    float s = 0.f;
#pragma unroll
    for (int c = 0; c < 16; ++c) s += part[c][tid];
    logits[(size_t)row * EE + tid] = s;
  }
}

// ---------------- route ----------------
__global__ __launch_bounds__(256) void k_route(const float* __restrict__ logits,
    int* __restrict__ cnt, int* __restrict__ listTok, int* __restrict__ tokslot,
    float* __restrict__ topw, float* __restrict__ psum) {
  int tid = threadIdx.x;
  int tok = blockIdx.x * 256 + tid;
  __shared__ int lcnt[16], gbase[16];
  __shared__ float lps[16];
  if (tid < 16) { lcnt[tid] = 0; lps[tid] = 0.f; }
  __syncthreads();
  float pr[16];
#pragma unroll
  for (int g = 0; g < 4; ++g) {
    float4 v = *(const float4*)&logits[(size_t)tok * EE + g * 4];
    pr[g*4+0] = v.x; pr[g*4+1] = v.y; pr[g*4+2] = v.z; pr[g*4+3] = v.w;
  }
  float mx = pr[0];
#pragma unroll
  for (int i = 1; i < 16; ++i) mx = fmaxf(mx, pr[i]);
  float s = 0.f;
#pragma unroll
  for (int i = 0; i < 16; ++i) { pr[i] = __expf(pr[i] - mx); s += pr[i]; }
  float inv = 1.0f / s;
#pragma unroll
  for (int i = 0; i < 16; ++i) pr[i] *= inv;
  int i1 = 0; float v1 = pr[0];
#pragma unroll
  for (int i = 1; i < 16; ++i) if (pr[i] > v1) { v1 = pr[i]; i1 = i; }
  int i2 = -1; float v2 = -1.f;
#pragma unroll
  for (int i = 0; i < 16; ++i) if (i != i1 && pr[i] > v2) { v2 = pr[i]; i2 = i; }
  float wsum = v1 + v2;
  int lp1 = atomicAdd(&lcnt[i1], 1);
  int lp2 = atomicAdd(&lcnt[i2], 1);
#pragma unroll
  for (int e = 0; e < 16; ++e) {
    float v = wred_sum(pr[e]);
    if ((tid & 63) == 0) atomicAdd(&lps[e], v);
  }
  __syncthreads();
  if (tid < 16) {
    gbase[tid] = atomicAdd(&cnt[tid], lcnt[tid]);
    atomicAdd(&psum[tid], lps[tid]);
  }
  __syncthreads();
  int p1 = gbase[i1] + lp1, p2 = gbase[i2] + lp2;
  listTok[i1 * 2048 + p1] = tok;
  listTok[i2 * 2048 + p2] = tok;
  tokslot[tok * 2 + 0] = i1 * 2048 + p1;
  tokslot[tok * 2 + 1] = i2 * 2048 + p2;
  topw[tok * 2 + 0] = v1 / wsum;
  topw[tok * 2 + 1] = v2 / wsum;
}

// ---------------- prefix + live-tile list (dense MoE grid) ----------------
__global__ void k_prefix(const int* __restrict__ cnt, int* __restrict__ offs,
                         int* __restrict__ tileE, int* __restrict__ tileM,
                         int* __restrict__ nTiles) {
  if (threadIdx.x == 0) {
    int s = 0, t = 0;
    for (int e = 0; e < 16; ++e) {
      offs[e] = s;
      for (int m0 = 0; m0 < cnt[e]; m0 += 128) { tileE[t] = e; tileM[t] = m0; ++t; }
      s += cnt[e];
    }
    nTiles[0] = t;
  }
}

// ---------------- MoE gate/up MFMA (r13: grid x=n, y=tile) ----------------
__global__ __launch_bounds__(256) void k_gu_mfma(const u16* __restrict__ tbh,
    const float* __restrict__ wg, const float* __restrict__ wu,
    const int* __restrict__ cnt, const int* __restrict__ offs,
    const int* __restrict__ listTok, const int* __restrict__ tileE,
    const int* __restrict__ tileM, const int* __restrict__ nTiles,
    u16* __restrict__ act) {
  int ti = blockIdx.y;
  if (ti >= nTiles[0]) return;
  int e = tileE[ti];
  int ce = cnt[e];
  int m0 = tileM[ti];
  int n0 = blockIdx.x * 64;
  __shared__ __align__(16) u16 Ah[128][56];
  __shared__ __align__(16) u16 Gh[64][56];
  __shared__ __align__(16) u16 Uh[64][56];
  __shared__ int rows[128];
  int tid = threadIdx.x;
  if (tid < 128) {
    int m = m0 + tid;
    rows[tid] = listTok[e * 2048 + (m < ce ? m : ce - 1)];
  }
  __syncthreads();
  int s_arow = tid >> 1, s_acol = (tid & 1) * 16;
  int s_nc = (tid & 31) * 2, s_kg = (tid >> 5) * 4;
  const float* wge = wg + (size_t)e * DD * II + n0;
  const float* wue = wu + (size_t)e * DD * II + n0;
  const u16* ap = tbh + (size_t)rows[s_arow] * DD + s_acol;
  int lane = tid & 63, w = tid >> 6;
  int wm = (w & 1) * 64, wn = (w >> 1) * 32;
  int lr = lane & 15, lk = (lane >> 4) * 8;
  f32x4 accg[4][2] = {};
  f32x4 accu[4][2] = {};
  for (int k0 = 0; k0 < DD; k0 += 32) {
    uint4 av0 = *(const uint4*)(ap + k0);
    uint4 av1 = *(const uint4*)(ap + k0 + 8);
    float2 g0 = *(const float2*)&wge[(size_t)(k0 + s_kg + 0) * II + s_nc];
    float2 g1 = *(const float2*)&wge[(size_t)(k0 + s_kg + 1) * II + s_nc];
    float2 g2 = *(const float2*)&wge[(size_t)(k0 + s_kg + 2) * II + s_nc];
    float2 g3 = *(const float2*)&wge[(size_t)(k0 + s_kg + 3) * II + s_nc];
    float2 u0 = *(const float2*)&wue[(size_t)(k0 + s_kg + 0) * II + s_nc];
    float2 u1 = *(const float2*)&wue[(size_t)(k0 + s_kg + 1) * II + s_nc];
    float2 u2 = *(const float2*)&wue[(size_t)(k0 + s_kg + 2) * II + s_nc];
    float2 u3 = *(const float2*)&wue[(size_t)(k0 + s_kg + 3) * II + s_nc];
    *(uint4*)&Ah[s_arow][s_acol]     = av0;
    *(uint4*)&Ah[s_arow][s_acol + 8] = av1;
    *(ushort4*)&Gh[s_nc][s_kg]     = make_ushort4(f2b(g0.x), f2b(g1.x), f2b(g2.x), f2b(g3.x));
    *(ushort4*)&Gh[s_nc + 1][s_kg] = make_ushort4(f2b(g0.y), f2b(g1.y), f2b(g2.y), f2b(g3.y));
    *(ushort4*)&Uh[s_nc][s_kg]     = make_ushort4(f2b(u0.x), f2b(u1.x), f2b(u2.x), f2b(u3.x));
    *(ushort4*)&Uh[s_nc + 1][s_kg] = make_ushort4(f2b(u0.y), f2b(u1.y), f2b(u2.y), f2b(u3.y));
    __syncthreads();
    bf16x8 af[4];
#pragma unroll
    for (int fm = 0; fm < 4; ++fm) af[fm] = ld_frag(&Ah[wm + fm*16 + lr][lk]);
#pragma unroll
    for (int nf = 0; nf < 2; ++nf) {
      bf16x8 bg = ld_frag(&Gh[wn + nf*16 + lr][lk]);
      bf16x8 bu = ld_frag(&Uh[wn + nf*16 + lr][lk]);
#pragma unroll
      for (int fm = 0; fm < 4; ++fm) {
        accg[fm][nf] = __builtin_amdgcn_mfma_f32_16x16x32_bf16(af[fm], bg, accg[fm][nf], 0, 0, 0);
        accu[fm][nf] = __builtin_amdgcn_mfma_f32_16x16x32_bf16(af[fm], bu, accu[fm][nf], 0, 0, 0);
      }
    }
    __syncthreads();
  }
  int ob = offs[e];
#pragma unroll
  for (int fm = 0; fm < 4; ++fm)
#pragma unroll
    for (int nf = 0; nf < 2; ++nf)
#pragma unroll
      for (int r = 0; r < 4; ++r) {
        int m = m0 + wm + fm*16 + (lane >> 4) * 4 + r;
        if (m < ce) {
          float g = accg[fm][nf][r], u = accu[fm][nf][r];
          float sv = (g / (1.f + __expf(-g))) * u;
          act[(size_t)(ob + m) * II + n0 + wn + nf*16 + (lane & 15)] = f2b(sv);
        }
      }
}

// ---------------- MoE down MFMA (r13: grid x=n, y=tile) ----------------
__global__ __launch_bounds__(256) void k_down_mfma(const u16* __restrict__ act,
    const float* __restrict__ wd, const int* __restrict__ cnt, const int* __restrict__ offs,
    const int* __restrict__ tileE, const int* __restrict__ tileM,
    const int* __restrict__ nTiles, float* __restrict__ eo) {
  int ti = blockIdx.y;
  if (ti >= nTiles[0]) return;
  int e = tileE[ti];
  int ce = cnt[e];
  int m0 = tileM[ti];
  int n0 = blockIdx.x * 64;
  __shared__ __align__(16) u16 Ah[128][56];
  __shared__ __align__(16) u16 Bh[64][56];
  int tid = threadIdx.x;
  int ob = offs[e];
  int s_arow = tid >> 1, s_acol = (tid & 1) * 16;
  int s_nc = (tid & 31) * 2, s_kg = (tid >> 5) * 4;
  int mrow = m0 + s_arow; if (mrow >= ce) mrow = ce - 1;
  const u16* ap = act + (size_t)(ob + mrow) * II + s_acol;
  const float* wde = wd + (size_t)e * II * DD + n0;
  int lane = tid & 63, w = tid >> 6;
  int wm = (w & 1) * 64, wn = (w >> 1) * 32;
  int lr = lane & 15, lk = (lane >> 4) * 8;
  f32x4 acc[4][2] = {};
  for (int k0 = 0; k0 < II; k0 += 32) {
    uint4 av0 = *(const uint4*)(ap + k0);
    uint4 av1 = *(const uint4*)(ap + k0 + 8);
    float2 b0 = *(const float2*)&wde[(size_t)(k0 + s_kg + 0) * DD + s_nc];
    float2 b1 = *(const float2*)&wde[(size_t)(k0 + s_kg + 1) * DD + s_nc];
    float2 b2 = *(const float2*)&wde[(size_t)(k0 + s_kg + 2) * DD + s_nc];
    float2 b3 = *(const float2*)&wde[(size_t)(k0 + s_kg + 3) * DD + s_nc];
    *(uint4*)&Ah[s_arow][s_acol]     = av0;
    *(uint4*)&Ah[s_arow][s_acol + 8] = av1;
    *(ushort4*)&Bh[s_nc][s_kg]     = make_ushort4(f2b(b0.x), f2b(b1.x), f2b(b2.x), f2b(b3.x));
    *(ushort4*)&Bh[s_nc + 1][s_kg] = make_ushort4(f2b(b0.y), f2b(b1.y), f2b(b2.y), f2b(b3.y));
    __syncthreads();
    bf16x8 af[4];
#pragma unroll
    for (int fm = 0; fm < 4; ++fm) af[fm] = ld_frag(&Ah[wm + fm*16 + lr][lk]);
#pragma unroll
    for (int nf = 0; nf < 2; ++nf) {
      bf16x8 bb = ld_frag(&Bh[wn + nf*16 + lr][lk]);
#pragma unroll
      for (int fm = 0; fm < 4; ++fm)
        acc[fm][nf] = __builtin_amdgcn_mfma_f32_16x16x32_bf16(af[fm], bb, acc[fm][nf], 0, 0, 0);
    }
    __syncthreads();
  }
#pragma unroll
  for (int fm = 0; fm < 4; ++fm)
#pragma unroll
    for (int nf = 0; nf < 2; ++nf)
#pragma unroll
      for (int r = 0; r < 4; ++r) {
        int m = m0 + wm + fm*16 + (lane >> 4) * 4 + r;
        if (m < ce)
          eo[(size_t)(ob + m) * DD + n0 + wn + nf*16 + (lane & 15)] = acc[fm][nf][r];
      }
}

// ---------------- final combine (+ aux in block 0) ----------------
__global__ __launch_bounds__(256) void k_final(const float* __restrict__ x2,
    const float* __restrict__ eo, const int* __restrict__ tokslot,
    const float* __restrict__ topw, const int* __restrict__ offs,
    const int* __restrict__ cnt, const float* __restrict__ psum,
    float* __restrict__ out) {
  int tok = blockIdx.x, tid = threadIdx.x;
  int c0 = tokslot[tok * 2], c1 = tokslot[tok * 2 + 1];
  int s0 = offs[c0 >> 11] + (c0 & 2047);
  int s1 = offs[c1 >> 11] + (c1 & 2047);
  float w0 = topw[tok * 2], w1 = topw[tok * 2 + 1];
  float4 a = ((const float4*)(x2 + (size_t)tok * DD))[tid];
  float4 e0 = ((const float4*)(eo + (size_t)s0 * DD))[tid];
  float4 e1 = ((const float4*)(eo + (size_t)s1 * DD))[tid];
  float4 o = make_float4(a.x + w0*e0.x + w1*e1.x, a.y + w0*e0.y + w1*e1.y,
                         a.z + w0*e0.z + w1*e1.z, a.w + w0*e0.w + w1*e1.w);
  ((float4*)(out + (size_t)tok * DD))[tid] = o;
  if (tok == 0 && tid == 0) {
    float acc = 0.f;
    for (int e = 0; e < 16; ++e)
      acc += ((float)cnt[e] * (1.0f / 4096.0f)) * (psum[e] * (1.0f / 2048.0f));
    out[(size_t)TT * DD] = 16.0f * acc;
  }
}

extern "C" void kernel_launch(void* const* d_in, const int* in_sizes, int n_in,
                              void* d_out, int out_size, void* d_ws, size_t ws_size,
                              hipStream_t stream) {
  const float* x    = (const float*)d_in[0];
  const float* cosb = (const float*)d_in[1];
  const float* sinb = (const float*)d_in[2];
  const float* ln1w = (const float*)d_in[3];
  const float* wq   = (const float*)d_in[4];
  const float* wk   = (const float*)d_in[5];
  const float* wv   = (const float*)d_in[6];
  const float* wo   = (const float*)d_in[7];
  const float* qnw  = (const float*)d_in[8];
  const float* knw  = (const float*)d_in[9];
  const float* ln2w = (const float*)d_in[10];
  const float* rw   = (const float*)d_in[11];
  const float* wg   = (const float*)d_in[12];
  const float* wu   = (const float*)d_in[13];
  const float* wd   = (const float*)d_in[14];
  float* out = (float*)d_out;

  float* W = (float*)d_ws;
  int*   cnt     = (int*)W;
  int*   offs    = (int*)(W + 16);
  float* psum    = W + 32;
  int*   tokslot = (int*)(W + 64);
  float* topw    = W + 4160;
  int*   listTok = (int*)(W + 8256);
  float* logits  = W + 41024;
  int*   tileE   = (int*)(W + 73728);
  int*   tileM   = (int*)(W + 73792);
  int*   nTiles  = (int*)(W + 73856);
  size_t o = 81920;
#define ALLOC_F(name, n)   float* name = W + o; o += (n);
#define ALLOC_U16(name, n) u16* name = (u16*)(W + o); o += ((size_t)(n) + 1) / 2;
  ALLOC_U16(h0, 2097152) ALLOC_U16(h1, 2097152)
  ALLOC_F(qb, 2097152) ALLOC_F(kb, 524288) ALLOC_F(vb, 524288)
  ALLOC_U16(wqt0, 1048576) ALLOC_U16(wqt1, 1048576)
  ALLOC_U16(wkt0, 262144) ALLOC_U16(wkt1, 262144)
  ALLOC_U16(wvt0, 262144) ALLOC_U16(wvt1, 262144)
  ALLOC_U16(wot0, 1048576) ALLOC_U16(wot1, 1048576)
  ALLOC_U16(qs0, 2097152) ALLOC_U16(qs1, 2097152)
  ALLOC_U16(ks0, 524288) ALLOC_U16(ks1, 524288)
  ALLOC_U16(vt0, 524288) ALLOC_U16(vt1, 524288)
  ALLOC_U16(at0, 2097152) ALLOC_U16(at1, 2097152)
  ALLOC_F(x2, 2097152)
  ALLOC_U16(tbh, 2097152)
  ALLOC_U16(act, 5767168)
  ALLOC_F(eo, 4194304)
#undef ALLOC_F
#undef ALLOC_U16

  k_rmsnorm_split2<<<TT, 256, 0, stream>>>(x, ln1w, h0, h1);
  k_transpose_all<<<640, 256, 0, stream>>>(wq, wk, wv, wo,
      wqt0, wqt1, wkt0, wkt1, wvt0, wvt1, wot0, wot1);
  k_qkv_s2<<<dim3(24, 16), 256, 0, stream>>>(h0, h1,
      wqt0, wqt1, wkt0, wkt1, wvt0, wvt1, qb, kb, vb);
  k_qknorm_rope_split2<<<dim3(TT, 5), 256, 0, stream>>>(qb, kb, qnw, knw, cosb, sinb,
      qs0, qs1, ks0, ks1);
  k_splitv2<<<dim3(16, 8), 256, 0, stream>>>(vb, vt0, vt1);
  k_flash<<<dim3(8, 32), 256, 0, stream>>>(qs0, qs1, ks0, ks1, vt0, vt1, at0, at1);
  k_wo_s2<<<dim3(16, 16), 256, 0, stream>>>(at0, at1, wot0, wot1, x, x2);
  k_rmsnorm_logits<<<TT, 256, 0, stream>>>(x2, ln2w, rw, tbh, logits, cnt, psum);
  k_route<<<TT / 256, 256, 0, stream>>>(logits, cnt, listTok, tokslot, topw, psum);
  k_prefix<<<1, 1, 0, stream>>>(cnt, offs, tileE, tileM, nTiles);
  k_gu_mfma<<<dim3(22, 48), 256, 0, stream>>>(tbh, wg, wu, cnt, offs, listTok,
      tileE, tileM, nTiles, act);
  k_down_mfma<<<dim3(16, 48), 256, 0, stream>>>(act, wd, cnt, offs,
      tileE, tileM, nTiles, eo);
  k_final<<<TT, 256, 0, stream>>>(x2, eo, tokslot, topw, offs, cnt, psum, out);
}